// Round 1
// baseline (224.885 us; speedup 1.0000x reference)
//
#include <hip/hip_runtime.h>
#include <math.h>

#define F 64
#define TILE 16
#define PAD 4   // pad y/z LDS rows to break bank alignment (stride 68 floats)

__device__ __forceinline__ float sigmoid_f(float x) {
    return 1.0f / (1.0f + __expf(-x));
}
__device__ __forceinline__ float silu_f(float x) {
    return x * (1.0f / (1.0f + __expf(-x)));
}

// ---------------------------------------------------------------------------
// Kernel 1: per-node precompute of half layer-1 outputs (bias folded in):
//   y[i][f] = 0.5 * sum_k x[i][k]*lW1[k][f] + 0.5*lb1[f]
//   z[i][f] = 0.5 * sum_k x[i][k]*gW1[k][f] + 0.5*gb1[f]
// grid = N blocks, 64 threads (thread = output feature f)
// ---------------------------------------------------------------------------
__global__ void precompute_yz(const float* __restrict__ x,
                              const float* __restrict__ lW1, const float* __restrict__ lb1,
                              const float* __restrict__ gW1, const float* __restrict__ gb1,
                              float* __restrict__ y, float* __restrict__ z) {
    __shared__ float xs[F];
    const int i = blockIdx.x;
    const int f = threadIdx.x;
    xs[f] = x[i * F + f];
    __syncthreads();
    float accY = 0.f, accZ = 0.f;
#pragma unroll
    for (int k = 0; k < F; ++k) {
        const float xv = xs[k];
        accY += xv * lW1[k * F + f];
        accZ += xv * gW1[k * F + f];
    }
    y[i * F + f] = 0.5f * accY + 0.5f * lb1[f];
    z[i * F + f] = 0.5f * accZ + 0.5f * gb1[f];
}

// ---------------------------------------------------------------------------
// Kernel 2: one thread per pair, 16x16 pair tile per block, upper triangle
// only (tile ti <= tj); result mirrored to both (i,j) and (j,i).
// ---------------------------------------------------------------------------
__global__ __launch_bounds__(256, 2) void pair_mlp(
    const float* __restrict__ y, const float* __restrict__ z,
    const float* __restrict__ lW2, const float* __restrict__ lb2,
    const float* __restrict__ lW3, const float* __restrict__ lb3,
    const float* __restrict__ gW2, const float* __restrict__ gb2,
    const float* __restrict__ gW3, const float* __restrict__ gb3,
    float* __restrict__ out, int N) {

    __shared__ float ysi[TILE][F + PAD];
    __shared__ float zsi[TILE][F + PAD];
    __shared__ float ysj[TILE][F + PAD];
    __shared__ float zsj[TILE][F + PAD];
    __shared__ float w2l[F][F];
    __shared__ float w2g[F][F];
    __shared__ float w3l[F], w3g[F], b2l[F], b2g[F];

    const int bid = blockIdx.x;
    // triangular decode: tj*(tj+1)/2 <= bid < (tj+1)(tj+2)/2, ti = remainder
    int tj = (int)((sqrtf(8.0f * (float)bid + 1.0f) - 1.0f) * 0.5f);
    while ((tj + 1) * (tj + 2) / 2 <= bid) ++tj;
    while (tj * (tj + 1) / 2 > bid) --tj;
    const int ti = bid - tj * (tj + 1) / 2;   // ti <= tj
    const int i0 = ti * TILE, j0 = tj * TILE;

    const int t = threadIdx.x;

    // ---- stage weights (2 x 64x64 fp32 = 32 KB) ----
    {
        const float4* s1 = (const float4*)lW2;
        const float4* s2 = (const float4*)gW2;
        float4* d1 = (float4*)&w2l[0][0];
        float4* d2 = (float4*)&w2g[0][0];
#pragma unroll
        for (int r = 0; r < 4; ++r) {
            d1[t + 256 * r] = s1[t + 256 * r];
            d2[t + 256 * r] = s2[t + 256 * r];
        }
    }
    if (t < F) {
        w3l[t] = lW3[t];
        w3g[t] = gW3[t];
        b2l[t] = lb2[t];
        b2g[t] = gb2[t];
    }
    // ---- stage y/z row blocks (4 x 16x64 fp32) ----
    {
        const int r = t >> 4;          // 0..15
        const int e4 = t & 15;         // float4 index within row
        const float4* yv = (const float4*)y;
        const float4* zv = (const float4*)z;
        *(float4*)&ysi[r][e4 * 4] = yv[(i0 + r) * (F / 4) + e4];
        *(float4*)&zsi[r][e4 * 4] = zv[(i0 + r) * (F / 4) + e4];
        *(float4*)&ysj[r][e4 * 4] = yv[(j0 + r) * (F / 4) + e4];
        *(float4*)&zsj[r][e4 * 4] = zv[(j0 + r) * (F / 4) + e4];
    }
    __syncthreads();

    const float b3l = lb3[0];
    const float b3g = gb3[0];

    const int tl = t >> 4;   // local row  (i)
    const int tc = t & 15;   // local col  (j)
    const int i = i0 + tl;
    const int j = j0 + tc;

    // ---- layer 1: activations from precomputed halves ----
    float m1[F];
    float g1[F];
#pragma unroll
    for (int f4 = 0; f4 < F / 4; ++f4) {
        const float4 a = *(const float4*)&ysi[tl][f4 * 4];
        const float4 b = *(const float4*)&ysj[tc][f4 * 4];
        m1[4 * f4 + 0] = silu_f(a.x + b.x);
        m1[4 * f4 + 1] = silu_f(a.y + b.y);
        m1[4 * f4 + 2] = silu_f(a.z + b.z);
        m1[4 * f4 + 3] = silu_f(a.w + b.w);
        const float4 c = *(const float4*)&zsi[tl][f4 * 4];
        const float4 d = *(const float4*)&zsj[tc][f4 * 4];
        g1[4 * f4 + 0] = silu_f(c.x + d.x);
        g1[4 * f4 + 1] = silu_f(c.y + d.y);
        g1[4 * f4 + 2] = silu_f(c.z + d.z);
        g1[4 * f4 + 3] = silu_f(c.w + d.w);
    }

    // ---- main branch: layer 2 (64x64) fused with layer 3 (64x1) ----
    float m3 = b3l;
#pragma unroll 1
    for (int f = 0; f < F; f += 4) {
        float4 acc = *(const float4*)&b2l[f];
#pragma unroll
        for (int k = 0; k < F; ++k) {
            const float4 w = *(const float4*)&w2l[k][f];  // wave-uniform broadcast
            const float mk = m1[k];
            acc.x += mk * w.x;
            acc.y += mk * w.y;
            acc.z += mk * w.z;
            acc.w += mk * w.w;
        }
        const float4 w3v = *(const float4*)&w3l[f];
        m3 += silu_f(acc.x) * w3v.x + silu_f(acc.y) * w3v.y +
              silu_f(acc.z) * w3v.z + silu_f(acc.w) * w3v.w;
    }

    // ---- gate branch: layer 2 fused with layer 3 ----
    float g3 = b3g;
#pragma unroll 1
    for (int f = 0; f < F; f += 4) {
        float4 acc = *(const float4*)&b2g[f];
#pragma unroll
        for (int k = 0; k < F; ++k) {
            const float4 w = *(const float4*)&w2g[k][f];  // wave-uniform broadcast
            const float gk = g1[k];
            acc.x += gk * w.x;
            acc.y += gk * w.y;
            acc.z += gk * w.z;
            acc.w += gk * w.w;
        }
        const float4 w3v = *(const float4*)&w3g[f];
        g3 += silu_f(acc.x) * w3v.x + silu_f(acc.y) * w3v.y +
              silu_f(acc.z) * w3v.z + silu_f(acc.w) * w3v.w;
    }

    const float val = m3 * sigmoid_f(g3);

    if (i < N && j < N) {
        out[i * N + j] = val;
        out[j * N + i] = val;   // symmetry: pair(i,j) == pair(j,i)
    }
}

extern "C" void kernel_launch(void* const* d_in, const int* in_sizes, int n_in,
                              void* d_out, int out_size, void* d_ws, size_t ws_size,
                              hipStream_t stream) {
    const float* node_feat = (const float*)d_in[0];
    const float* lW1 = (const float*)d_in[1];
    const float* lb1 = (const float*)d_in[2];
    const float* lW2 = (const float*)d_in[3];
    const float* lb2 = (const float*)d_in[4];
    const float* lW3 = (const float*)d_in[5];
    const float* lb3 = (const float*)d_in[6];
    const float* gW1 = (const float*)d_in[7];
    const float* gb1 = (const float*)d_in[8];
    const float* gW2 = (const float*)d_in[9];
    const float* gb2 = (const float*)d_in[10];
    const float* gW3 = (const float*)d_in[11];
    const float* gb3 = (const float*)d_in[12];

    const int N = in_sizes[0] / F;   // 1024

    float* y = (float*)d_ws;                   // N*F floats
    float* z = y + (size_t)N * F;              // N*F floats

    // Kernel 1: per-node half layer-1 outputs
    precompute_yz<<<N, F, 0, stream>>>(node_feat, lW1, lb1, gW1, gb1, y, z);

    // Kernel 2: upper-triangle pair tiles
    const int nT = N / TILE;                   // 64
    const int nBlocks = nT * (nT + 1) / 2;     // 2080
    pair_mlp<<<nBlocks, 256, 0, stream>>>(y, z,
                                          lW2, lb2, lW3, lb3,
                                          gW2, gb2, gW3, gb3,
                                          (float*)d_out, N);
}

// Round 2
// 101.876 us; speedup vs baseline: 2.2074x; 2.2074x over previous
//
#include <hip/hip_runtime.h>
#include <hip/hip_bf16.h>
#include <math.h>

#define F 64
#define TILE 16

typedef __attribute__((ext_vector_type(8))) short bf16x8;
typedef __attribute__((ext_vector_type(4))) float f32x4;

__device__ __forceinline__ float sigmoid_f(float x) {
    return 1.0f / (1.0f + __expf(-x));
}
__device__ __forceinline__ float silu_f(float x) {
    return x * (1.0f / (1.0f + __expf(-x)));
}
__device__ __forceinline__ short f2bf(float x) {
    __hip_bfloat16 h = __float2bfloat16(x);
    return __builtin_bit_cast(short, h);
}

// ---------------------------------------------------------------------------
// Kernel 1: per-node half layer-1 outputs (bias folded):
//   y[i][f] = 0.5*(x[i]@lW1)[f] + 0.5*lb1[f];  z likewise for gate branch.
// ---------------------------------------------------------------------------
__global__ void precompute_yz(const float* __restrict__ x,
                              const float* __restrict__ lW1, const float* __restrict__ lb1,
                              const float* __restrict__ gW1, const float* __restrict__ gb1,
                              float* __restrict__ y, float* __restrict__ z) {
    __shared__ float xs[F];
    const int i = blockIdx.x;
    const int f = threadIdx.x;
    xs[f] = x[i * F + f];
    __syncthreads();
    float accY = 0.f, accZ = 0.f;
#pragma unroll
    for (int k = 0; k < F; ++k) {
        const float xv = xs[k];
        accY += xv * lW1[k * F + f];
        accZ += xv * gW1[k * F + f];
    }
    y[i * F + f] = 0.5f * accY + 0.5f * lb1[f];
    z[i * F + f] = 0.5f * accZ + 0.5f * gb1[f];
}

// ---------------------------------------------------------------------------
// Kernel 2: pre-swizzle layer-2 weights into per-lane MFMA B-fragments,
// split into bf16 hi + lo. Element layout (shorts):
//   wf[ b*8192 + kt*4096 + nt*1024 + s*512 + lane*8 + e ]
//   = W_b[k][c],  k = kt*32 + (lane>>4)*8 + e,  c = nt*16 + (lane&15)
//   s=0: bf16(w), s=1: bf16(w - float(bf16(w)))
// ---------------------------------------------------------------------------
__global__ void prep_wfrags(const float* __restrict__ lW2,
                            const float* __restrict__ gW2,
                            short* __restrict__ wf) {
    const int idx = blockIdx.x * 256 + threadIdx.x;   // 0..16383
    const int e    = idx & 7;
    const int lane = (idx >> 3) & 63;
    const int s    = (idx >> 9) & 1;
    const int nt   = (idx >> 10) & 3;
    const int kt   = (idx >> 12) & 1;
    const int b    = (idx >> 13) & 1;
    const int k = kt * 32 + ((lane >> 4) << 3) + e;
    const int c = nt * 16 + (lane & 15);
    const float* W = b ? gW2 : lW2;
    const float w = W[k * F + c];
    const __hip_bfloat16 hi = __float2bfloat16(w);
    float v;
    if (s == 0) {
        v = w;                      // will be rounded to hi below
    } else {
        v = w - __bfloat162float(hi);
    }
    wf[idx] = f2bf(v);
}

// ---------------------------------------------------------------------------
// One branch of the gated MLP for a wave's 64 pairs:
//   A = silu(si_row + sj_row) [64x64] bf16; out2 = A @ (Bhi+Blo); then
//   part[mt][r] = sum over this lane's cols of silu(out2 + b2)*w3.
// ---------------------------------------------------------------------------
__device__ __forceinline__ void run_branch(
    const float (*si)[F + 4], const float (*sj)[F + 4],
    const short* __restrict__ wfb,       // branch base (8192 shorts)
    const float* sB2, const float* sW3,
    int w, int l, float (&part)[4][4]) {

    const int g = l >> 4;
    const int c = l & 15;

    // ---- load B fragments (hi+lo) for this branch ----
    bf16x8 bh[2][4], bl[2][4];
#pragma unroll
    for (int kt = 0; kt < 2; ++kt)
#pragma unroll
        for (int nt = 0; nt < 4; ++nt) {
            const short* basep = wfb + kt * 4096 + nt * 1024;
            bh[kt][nt] = ((const bf16x8*)(basep))[l];
            bl[kt][nt] = ((const bf16x8*)(basep + 512))[l];
        }

    f32x4 acc[4][4];
#pragma unroll
    for (int mt = 0; mt < 4; ++mt)
#pragma unroll
        for (int nt = 0; nt < 4; ++nt)
            acc[mt][nt] = (f32x4){0.f, 0.f, 0.f, 0.f};

#pragma unroll
    for (int mt = 0; mt < 4; ++mt) {
        // ---- build A fragments: lane holds act1[row=l&15][k], k=kt*32+8g+e ----
        bf16x8 af[2];
#pragma unroll
        for (int kt = 0; kt < 2; ++kt) {
            const float* pi = &si[4 * w + mt][kt * 32 + 8 * g];   // wave-uniform row
            const float* pj = &sj[c][kt * 32 + 8 * g];
            const float4 i0v = *(const float4*)(pi);
            const float4 i1v = *(const float4*)(pi + 4);
            const float4 j0v = *(const float4*)(pj);
            const float4 j1v = *(const float4*)(pj + 4);
            af[kt][0] = f2bf(silu_f(i0v.x + j0v.x));
            af[kt][1] = f2bf(silu_f(i0v.y + j0v.y));
            af[kt][2] = f2bf(silu_f(i0v.z + j0v.z));
            af[kt][3] = f2bf(silu_f(i0v.w + j0v.w));
            af[kt][4] = f2bf(silu_f(i1v.x + j1v.x));
            af[kt][5] = f2bf(silu_f(i1v.y + j1v.y));
            af[kt][6] = f2bf(silu_f(i1v.z + j1v.z));
            af[kt][7] = f2bf(silu_f(i1v.w + j1v.w));
        }
#pragma unroll
        for (int nt = 0; nt < 4; ++nt) {
            acc[mt][nt] = __builtin_amdgcn_mfma_f32_16x16x32_bf16(af[0], bh[0][nt], acc[mt][nt], 0, 0, 0);
            acc[mt][nt] = __builtin_amdgcn_mfma_f32_16x16x32_bf16(af[0], bl[0][nt], acc[mt][nt], 0, 0, 0);
            acc[mt][nt] = __builtin_amdgcn_mfma_f32_16x16x32_bf16(af[1], bh[1][nt], acc[mt][nt], 0, 0, 0);
            acc[mt][nt] = __builtin_amdgcn_mfma_f32_16x16x32_bf16(af[1], bl[1][nt], acc[mt][nt], 0, 0, 0);
        }
    }

    // ---- fused layer 3 partials (this lane's cols: nt*16 + c) ----
#pragma unroll
    for (int mt = 0; mt < 4; ++mt)
#pragma unroll
        for (int r = 0; r < 4; ++r)
            part[mt][r] = 0.f;
#pragma unroll
    for (int nt = 0; nt < 4; ++nt) {
        const float b2v = sB2[nt * 16 + c];
        const float w3v = sW3[nt * 16 + c];
#pragma unroll
        for (int mt = 0; mt < 4; ++mt)
#pragma unroll
            for (int r = 0; r < 4; ++r)
                part[mt][r] += silu_f(acc[mt][nt][r] + b2v) * w3v;
    }
}

// ---------------------------------------------------------------------------
// Kernel 3: 16x16 pair tile per block (upper triangle), MFMA layer 2.
// ---------------------------------------------------------------------------
__global__ __launch_bounds__(256, 2) void pair_mlp_mfma(
    const float* __restrict__ y, const float* __restrict__ z,
    const short* __restrict__ wf,
    const float* __restrict__ lb2, const float* __restrict__ lW3, const float* __restrict__ lb3,
    const float* __restrict__ gb2, const float* __restrict__ gW3, const float* __restrict__ gb3,
    float* __restrict__ out, int N) {

    __shared__ float ysi[TILE][F + 4];
    __shared__ float zsi[TILE][F + 4];
    __shared__ float ysj[TILE][F + 4];
    __shared__ float zsj[TILE][F + 4];
    __shared__ float sB2l[F], sW3l[F], sB2g[F], sW3g[F];
    __shared__ float valD[TILE][TILE + 1];
    __shared__ float valT[TILE][TILE + 1];

    const int bid = blockIdx.x;
    int tj = (int)((sqrtf(8.0f * (float)bid + 1.0f) - 1.0f) * 0.5f);
    while ((tj + 1) * (tj + 2) / 2 <= bid) ++tj;
    while (tj * (tj + 1) / 2 > bid) --tj;
    const int ti = bid - tj * (tj + 1) / 2;   // ti <= tj
    const int i0 = ti * TILE, j0 = tj * TILE;

    const int t = threadIdx.x;

    // ---- stage y/z row tiles ----
    {
        const int r = t >> 4;
        const int e4 = t & 15;
        const float4* yv = (const float4*)y;
        const float4* zv = (const float4*)z;
        *(float4*)&ysi[r][e4 * 4] = yv[(size_t)(i0 + r) * (F / 4) + e4];
        *(float4*)&zsi[r][e4 * 4] = zv[(size_t)(i0 + r) * (F / 4) + e4];
        *(float4*)&ysj[r][e4 * 4] = yv[(size_t)(j0 + r) * (F / 4) + e4];
        *(float4*)&zsj[r][e4 * 4] = zv[(size_t)(j0 + r) * (F / 4) + e4];
    }
    if (t < F) {
        sB2l[t] = lb2[t];
        sW3l[t] = lW3[t];
        sB2g[t] = gb2[t];
        sW3g[t] = gW3[t];
    }
    __syncthreads();

    const int w = t >> 6;     // wave 0..3
    const int l = t & 63;
    const int g = l >> 4;
    const int c = l & 15;

    float partL[4][4], partG[4][4];
    run_branch(ysi, ysj, wf,        sB2l, sW3l, w, l, partL);
    run_branch(zsi, zsj, wf + 8192, sB2g, sW3g, w, l, partG);

    // ---- reduce over the 16 cols held by this lane group ----
#pragma unroll
    for (int m = 1; m < 16; m <<= 1) {
#pragma unroll
        for (int mt = 0; mt < 4; ++mt)
#pragma unroll
            for (int r = 0; r < 4; ++r) {
                partL[mt][r] += __shfl_xor(partL[mt][r], m, 64);
                partG[mt][r] += __shfl_xor(partG[mt][r], m, 64);
            }
    }

    const float b3l = lb3[0];
    const float b3g = gb3[0];

    // lane (g, c==r) owns pair (tl = 4w+mt, tc = 4g+r)
#pragma unroll
    for (int mt = 0; mt < 4; ++mt)
#pragma unroll
        for (int r = 0; r < 4; ++r) {
            if (c == r) {
                const float m3 = partL[mt][r] + b3l;
                const float g3 = partG[mt][r] + b3g;
                const float v = m3 * sigmoid_f(g3);
                valD[4 * w + mt][4 * g + r] = v;
                valT[4 * g + r][4 * w + mt] = v;
            }
        }
    __syncthreads();

    // ---- coalesced stores of both mirrored tiles ----
    {
        const int r = t >> 4;
        const int cc = t & 15;
        out[(size_t)(i0 + r) * N + (j0 + cc)] = valD[r][cc];
        out[(size_t)(j0 + r) * N + (i0 + cc)] = valT[r][cc];
    }
}

extern "C" void kernel_launch(void* const* d_in, const int* in_sizes, int n_in,
                              void* d_out, int out_size, void* d_ws, size_t ws_size,
                              hipStream_t stream) {
    const float* node_feat = (const float*)d_in[0];
    const float* lW1 = (const float*)d_in[1];
    const float* lb1 = (const float*)d_in[2];
    const float* lW2 = (const float*)d_in[3];
    const float* lb2 = (const float*)d_in[4];
    const float* lW3 = (const float*)d_in[5];
    const float* lb3 = (const float*)d_in[6];
    const float* gW1 = (const float*)d_in[7];
    const float* gb1 = (const float*)d_in[8];
    const float* gW2 = (const float*)d_in[9];
    const float* gb2 = (const float*)d_in[10];
    const float* gW3 = (const float*)d_in[11];
    const float* gb3 = (const float*)d_in[12];

    const int N = in_sizes[0] / F;   // 1024

    float* y = (float*)d_ws;                     // N*F floats
    float* z = y + (size_t)N * F;                // N*F floats
    short* wfrag = (short*)(z + (size_t)N * F);  // 16384 shorts (32 KB)

    precompute_yz<<<N, F, 0, stream>>>(node_feat, lW1, lb1, gW1, gb1, y, z);
    prep_wfrags<<<64, 256, 0, stream>>>(lW2, gW2, wfrag);

    const int nT = N / TILE;                   // 64
    const int nBlocks = nT * (nT + 1) / 2;     // 2080
    pair_mlp_mfma<<<nBlocks, 256, 0, stream>>>(y, z, wfrag,
                                               lb2, lW3, lb3,
                                               gb2, gW3, gb3,
                                               (float*)d_out, N);
}

// Round 3
// 72.093 us; speedup vs baseline: 3.1194x; 1.4131x over previous
//
#include <hip/hip_runtime.h>
#include <hip/hip_bf16.h>
#include <math.h>

#define F 64
#define TILE 16

typedef __attribute__((ext_vector_type(8))) short bf16x8;
typedef __attribute__((ext_vector_type(4))) float f32x4;

union BF8 { bf16x8 v; unsigned u[4]; };

#define LOG2E 1.4426950408889634f

__device__ __forceinline__ float fast_exp(float x) {          // e^x
    return __builtin_amdgcn_exp2f(x * LOG2E);
}
__device__ __forceinline__ float fast_sigmoid(float x) {
    return __builtin_amdgcn_rcpf(1.0f + fast_exp(-x));
}
__device__ __forceinline__ float fast_silu(float x) {
    return x * __builtin_amdgcn_rcpf(1.0f + fast_exp(-x));
}
// pack two floats to bf16 pair (round-half-up; inputs finite)
__device__ __forceinline__ unsigned pk2(float a, float b) {
    const unsigned ua = __builtin_bit_cast(unsigned, a);
    const unsigned ub = __builtin_bit_cast(unsigned, b);
    return ((ua + 0x8000u) >> 16) | ((ub + 0x8000u) & 0xFFFF0000u);
}
__device__ __forceinline__ short f2bf(float x) {
    __hip_bfloat16 h = __float2bfloat16(x);
    return __builtin_bit_cast(short, h);
}

// ---------------------------------------------------------------------------
// Kernel 1: per-node half layer-1 outputs (bias folded):
//   y[i][f] = 0.5*(x[i]@lW1)[f] + 0.5*lb1[f];  z likewise for gate branch.
// ---------------------------------------------------------------------------
__global__ void precompute_yz(const float* __restrict__ x,
                              const float* __restrict__ lW1, const float* __restrict__ lb1,
                              const float* __restrict__ gW1, const float* __restrict__ gb1,
                              float* __restrict__ y, float* __restrict__ z) {
    __shared__ float xs[F];
    const int i = blockIdx.x;
    const int f = threadIdx.x;
    xs[f] = x[i * F + f];
    __syncthreads();
    float accY = 0.f, accZ = 0.f;
#pragma unroll
    for (int k = 0; k < F; ++k) {
        const float xv = xs[k];
        accY += xv * lW1[k * F + f];
        accZ += xv * gW1[k * F + f];
    }
    y[i * F + f] = 0.5f * accY + 0.5f * lb1[f];
    z[i * F + f] = 0.5f * accZ + 0.5f * gb1[f];
}

// ---------------------------------------------------------------------------
// Kernel 2: pre-swizzle layer-2 weights into per-lane MFMA fragments
// (A-fragment of W^T == B-fragment of W in the m89 layout), hi+lo bf16 split.
//   wf[ b*8192 + kt*4096 + ft*1024 + s*512 + lane*8 + e ]
//   = W_b[k][f],  k = kt*32 + (lane>>4)*8 + e,  f = ft*16 + (lane&15)
//   s=0: bf16(w), s=1: bf16(w - float(bf16(w)))
// ---------------------------------------------------------------------------
__global__ void prep_wfrags(const float* __restrict__ lW2,
                            const float* __restrict__ gW2,
                            short* __restrict__ wf) {
    const int idx = blockIdx.x * 256 + threadIdx.x;   // 0..16383
    const int e    = idx & 7;
    const int lane = (idx >> 3) & 63;
    const int s    = (idx >> 9) & 1;
    const int ft   = (idx >> 10) & 3;
    const int kt   = (idx >> 12) & 1;
    const int b    = (idx >> 13) & 1;
    const int k = kt * 32 + ((lane >> 4) << 3) + e;
    const int f = ft * 16 + (lane & 15);
    const float* W = b ? gW2 : lW2;
    const float w = W[k * F + f];
    const __hip_bfloat16 hi = __float2bfloat16(w);
    const float v = (s == 0) ? w : (w - __bfloat162float(hi));
    wf[idx] = f2bf(v);
}

// ---------------------------------------------------------------------------
// One branch: out2^T = (W2hi+W2lo)^T @ act1^T via MFMA, fused layer 3.
// Wave w owns pairs (i_local = 4w+pt, j_local = 0..15).
// Output: part[pt] = sum over this lane's 16 features of silu(out2+b2)*w3;
// full sum after shfl-reduce over lane groups g.
// ---------------------------------------------------------------------------
__device__ __forceinline__ void run_branch(
    const float (*si)[F + 4], const float (*sj)[F + 4],
    const short* __restrict__ wfb,       // branch base (8192 shorts)
    const float* sB2, const float* sW3,
    int w, int g, int c, float (&part)[4]) {

    // ---- build act1^T B-fragments: lane holds act1[p = l&15][k = kt*32+8g+e]
    BF8 bfrag[2][4];
#pragma unroll
    for (int kt = 0; kt < 2; ++kt) {
        const float* pj = &sj[c][kt * 32 + 8 * g];
        const float4 j0v = *(const float4*)(pj);
        const float4 j1v = *(const float4*)(pj + 4);
#pragma unroll
        for (int pt = 0; pt < 4; ++pt) {
            const float* pi = &si[4 * w + pt][kt * 32 + 8 * g];  // wave-uniform
            const float4 i0v = *(const float4*)(pi);
            const float4 i1v = *(const float4*)(pi + 4);
            bfrag[kt][pt].u[0] = pk2(fast_silu(i0v.x + j0v.x), fast_silu(i0v.y + j0v.y));
            bfrag[kt][pt].u[1] = pk2(fast_silu(i0v.z + j0v.z), fast_silu(i0v.w + j0v.w));
            bfrag[kt][pt].u[2] = pk2(fast_silu(i1v.x + j1v.x), fast_silu(i1v.y + j1v.y));
            bfrag[kt][pt].u[3] = pk2(fast_silu(i1v.z + j1v.z), fast_silu(i1v.w + j1v.w));
        }
    }

    part[0] = part[1] = part[2] = part[3] = 0.f;
    const int l = g * 16 + c;

#pragma unroll
    for (int ft = 0; ft < 4; ++ft) {
        // W fragments for this feature tile (hi+lo, both k halves)
        const short* base = wfb + ft * 1024 + l * 8;
        const bf16x8 wh0 = *(const bf16x8*)(base);
        const bf16x8 wl0 = *(const bf16x8*)(base + 512);
        const bf16x8 wh1 = *(const bf16x8*)(base + 4096);
        const bf16x8 wl1 = *(const bf16x8*)(base + 4096 + 512);

        f32x4 acc[4];
#pragma unroll
        for (int pt = 0; pt < 4; ++pt) {
            acc[pt] = (f32x4){0.f, 0.f, 0.f, 0.f};
            acc[pt] = __builtin_amdgcn_mfma_f32_16x16x32_bf16(wh0, bfrag[0][pt].v, acc[pt], 0, 0, 0);
            acc[pt] = __builtin_amdgcn_mfma_f32_16x16x32_bf16(wl0, bfrag[0][pt].v, acc[pt], 0, 0, 0);
            acc[pt] = __builtin_amdgcn_mfma_f32_16x16x32_bf16(wh1, bfrag[1][pt].v, acc[pt], 0, 0, 0);
            acc[pt] = __builtin_amdgcn_mfma_f32_16x16x32_bf16(wl1, bfrag[1][pt].v, acc[pt], 0, 0, 0);
        }

        // fused layer 3: this lane's features f = ft*16 + 4g + r
        const float4 b2v = *(const float4*)&sB2[ft * 16 + 4 * g];
        const float4 w3v = *(const float4*)&sW3[ft * 16 + 4 * g];
#pragma unroll
        for (int pt = 0; pt < 4; ++pt) {
            part[pt] += fast_silu(acc[pt][0] + b2v.x) * w3v.x
                      + fast_silu(acc[pt][1] + b2v.y) * w3v.y
                      + fast_silu(acc[pt][2] + b2v.z) * w3v.z
                      + fast_silu(acc[pt][3] + b2v.w) * w3v.w;
        }
    }
}

// ---------------------------------------------------------------------------
// Kernel 3: 16x16 pair tile per block (upper triangle), transposed MFMA.
// ---------------------------------------------------------------------------
__global__ __launch_bounds__(256, 4) void pair_mlp_mfma(
    const float* __restrict__ y, const float* __restrict__ z,
    const short* __restrict__ wf,
    const float* __restrict__ lb2, const float* __restrict__ lW3, const float* __restrict__ lb3,
    const float* __restrict__ gb2, const float* __restrict__ gW3, const float* __restrict__ gb3,
    float* __restrict__ out, int N) {

    __shared__ float ysi[TILE][F + 4];
    __shared__ float zsi[TILE][F + 4];
    __shared__ float ysj[TILE][F + 4];
    __shared__ float zsj[TILE][F + 4];
    __shared__ float sB2l[F], sW3l[F], sB2g[F], sW3g[F];
    __shared__ float valT[TILE][TILE + 1];

    const int bid = blockIdx.x;
    int tj = (int)((sqrtf(8.0f * (float)bid + 1.0f) - 1.0f) * 0.5f);
    while ((tj + 1) * (tj + 2) / 2 <= bid) ++tj;
    while (tj * (tj + 1) / 2 > bid) --tj;
    const int ti = bid - tj * (tj + 1) / 2;   // ti <= tj
    const int i0 = ti * TILE, j0 = tj * TILE;

    const int t = threadIdx.x;

    // ---- stage y/z row tiles ----
    {
        const int r = t >> 4;
        const int e4 = t & 15;
        const float4* yv = (const float4*)y;
        const float4* zv = (const float4*)z;
        *(float4*)&ysi[r][e4 * 4] = yv[(size_t)(i0 + r) * (F / 4) + e4];
        *(float4*)&zsi[r][e4 * 4] = zv[(size_t)(i0 + r) * (F / 4) + e4];
        *(float4*)&ysj[r][e4 * 4] = yv[(size_t)(j0 + r) * (F / 4) + e4];
        *(float4*)&zsj[r][e4 * 4] = zv[(size_t)(j0 + r) * (F / 4) + e4];
    }
    if (t < F) {
        sB2l[t] = lb2[t];
        sW3l[t] = lW3[t];
        sB2g[t] = gb2[t];
        sW3g[t] = gW3[t];
    }
    __syncthreads();

    const int w = t >> 6;     // wave 0..3
    const int l = t & 63;
    const int g = l >> 4;
    const int c = l & 15;

    float partL[4], partG[4];
    run_branch(ysi, ysj, wf,        sB2l, sW3l, w, g, c, partL);
    run_branch(zsi, zsj, wf + 8192, sB2g, sW3g, w, g, c, partG);

    // ---- reduce across the 4 lane groups (features) ----
#pragma unroll
    for (int pt = 0; pt < 4; ++pt) {
        partL[pt] += __shfl_xor(partL[pt], 16, 64);
        partL[pt] += __shfl_xor(partL[pt], 32, 64);
        partG[pt] += __shfl_xor(partG[pt], 16, 64);
        partG[pt] += __shfl_xor(partG[pt], 32, 64);
    }

    const float b3l = lb3[0];
    const float b3g = gb3[0];

    if (g == 0) {
#pragma unroll
        for (int pt = 0; pt < 4; ++pt) {
            const float m3 = partL[pt] + b3l;
            const float g3 = partG[pt] + b3g;
            const float v = m3 * fast_sigmoid(g3);
            out[(size_t)(i0 + 4 * w + pt) * N + (j0 + c)] = v;   // coalesced
            valT[c][4 * w + pt] = v;
        }
    }
    __syncthreads();

    // ---- transposed mirror tile, coalesced ----
    {
        const int r = t >> 4;
        const int cc = t & 15;
        out[(size_t)(j0 + r) * N + (i0 + cc)] = valT[r][cc];
    }
}

extern "C" void kernel_launch(void* const* d_in, const int* in_sizes, int n_in,
                              void* d_out, int out_size, void* d_ws, size_t ws_size,
                              hipStream_t stream) {
    const float* node_feat = (const float*)d_in[0];
    const float* lW1 = (const float*)d_in[1];
    const float* lb1 = (const float*)d_in[2];
    const float* lW2 = (const float*)d_in[3];
    const float* lb2 = (const float*)d_in[4];
    const float* lW3 = (const float*)d_in[5];
    const float* lb3 = (const float*)d_in[6];
    const float* gW1 = (const float*)d_in[7];
    const float* gb1 = (const float*)d_in[8];
    const float* gW2 = (const float*)d_in[9];
    const float* gb2 = (const float*)d_in[10];
    const float* gW3 = (const float*)d_in[11];
    const float* gb3 = (const float*)d_in[12];

    const int N = in_sizes[0] / F;   // 1024

    float* y = (float*)d_ws;                     // N*F floats
    float* z = y + (size_t)N * F;                // N*F floats
    short* wfrag = (short*)(z + (size_t)N * F);  // 16384 shorts (32 KB)

    precompute_yz<<<N, F, 0, stream>>>(node_feat, lW1, lb1, gW1, gb1, y, z);
    prep_wfrags<<<64, 256, 0, stream>>>(lW2, gW2, wfrag);

    const int nT = N / TILE;                   // 64
    const int nBlocks = nT * (nT + 1) / 2;     // 2080
    pair_mlp_mfma<<<nBlocks, 256, 0, stream>>>(y, z, wfrag,
                                               lb2, lW3, lb3,
                                               gb2, gW3, gb3,
                                               (float*)d_out, N);
}